// Round 1
// baseline (50.695 us; speedup 1.0000x reference)
//
#include <hip/hip_runtime.h>

// Problem constants (from reference):
//   B=8, T=128, C=32, H=32, W=32  -> CHW = 32768, N = B*CHW = 262144
//   THRESHOLD = 1.0, MEMBRANE_SUBTRACT = 1.0
// Per-neuron sequential scan over T:
//   cum += x[t]; v = cum - sub; s = (v >= 1) ? floor(v) : 0; sub += s; out[t] = s
// Layout [B, T, C, H, W]: flat idx(b,t,n) = (b*T + t)*CHW + n, n in [0,CHW).
// Thread = 4 consecutive neurons (float4), loop over t (stride CHW floats).

constexpr int kT   = 128;
constexpr int kCHW = 32 * 32 * 32;        // 32768
constexpr int kQPB = kCHW / 4;            // quads per batch = 8192

__global__ __launch_bounds__(256) void iaf_scan_kernel(
    const float4* __restrict__ in, float4* __restrict__ out) {
  const int gid = blockIdx.x * blockDim.x + threadIdx.x;   // [0, B*kQPB)
  const int b = gid >> 13;            // gid / 8192
  const int q = gid & (kQPB - 1);     // gid % 8192

  const size_t base = (size_t)b * kT * kQPB + q;
  const float4* __restrict__ ip = in + base;
  float4* __restrict__ op = out + base;

  float4 cum = make_float4(0.f, 0.f, 0.f, 0.f);
  float4 sub = make_float4(0.f, 0.f, 0.f, 0.f);

#pragma unroll 4
  for (int t = 0; t < kT; ++t) {
    const float4 x = ip[(size_t)t * kQPB];
    float4 s;

    cum.x += x.x;
    { float v = cum.x - sub.x; s.x = (v >= 1.0f) ? floorf(v) : 0.0f; sub.x += s.x; }
    cum.y += x.y;
    { float v = cum.y - sub.y; s.y = (v >= 1.0f) ? floorf(v) : 0.0f; sub.y += s.y; }
    cum.z += x.z;
    { float v = cum.z - sub.z; s.z = (v >= 1.0f) ? floorf(v) : 0.0f; sub.z += s.z; }
    cum.w += x.w;
    { float v = cum.w - sub.w; s.w = (v >= 1.0f) ? floorf(v) : 0.0f; sub.w += s.w; }

    op[(size_t)t * kQPB] = s;
  }
}

extern "C" void kernel_launch(void* const* d_in, const int* in_sizes, int n_in,
                              void* d_out, int out_size, void* d_ws, size_t ws_size,
                              hipStream_t stream) {
  (void)in_sizes; (void)n_in; (void)d_ws; (void)ws_size; (void)out_size;
  const float4* in = (const float4*)d_in[0];
  float4* out = (float4*)d_out;

  const int total_threads = 8 * kQPB;          // 65536
  const int block = 256;
  const int grid = total_threads / block;      // 256
  iaf_scan_kernel<<<grid, block, 0, stream>>>(in, out);
}

// Round 2
// 44.539 us; speedup vs baseline: 1.1382x; 1.1382x over previous
//
#include <hip/hip_runtime.h>

// IAF multi-spike scan, B=8, T=128, C*H*W=32768, threshold=subtract=1.
// Layout [B, T, CHW]: idx(b,t,n) = (b*T + t)*CHW + n.
//
// Closed form (valid for NON-NEGATIVE inputs, which spike counts are):
//   sub_t = floor(cum_t)  =>  s_t = floor(cum_t) - floor(cum_{t-1})
// Proof sketch: residual r_t = cum_t - sub_t stays in [0,1);
// floor(int + y) = int + floor(y). This makes the T-scan a prefix sum,
// so T can be chunked for parallelism.
//
// Structure: thread = (quad of 4 neurons, chunk of 16 timesteps).
//   Phase 1: load 16 float4 of own chunk into regs, compute chunk sum.
//   Phase 2: LDS exchange -> exclusive prefix of chunk sums per quad.
//   Phase 3: cum = prefix; emit s = floor(cum_t) - floor(cum_{t-1}).

constexpr int kT     = 128;
constexpr int kQPB   = 32 * 32 * 32 / 4;   // 8192 float4-quads per (b,t) slice
constexpr int kNC    = 8;                  // chunks over T
constexpr int kCL    = kT / kNC;           // 16 timesteps per chunk
constexpr int kQPBlk = 32;                 // quads per block (256 thr = 32q x 8c)

__global__ __launch_bounds__(256) void iaf_scan_kernel(
    const float4* __restrict__ in, float4* __restrict__ out) {
  __shared__ float4 csums[kNC][kQPBlk];

  const int tid = threadIdx.x;
  const int ql  = tid & (kQPBlk - 1);      // quad within block
  const int c   = tid >> 5;                // chunk index

  const int gq = blockIdx.x * kQPBlk + ql; // global quad in [0, 65536)
  const int b  = gq >> 13;                 // / 8192
  const int q  = gq & (kQPB - 1);          // % 8192

  const size_t base = (size_t)b * kT * kQPB + q + (size_t)c * kCL * kQPB;
  const float4* __restrict__ ip = in + base;
  float4* __restrict__ op = out + base;

  // Phase 1: 16 independent loads in flight, then chunk sum.
  float4 x[kCL];
#pragma unroll
  for (int i = 0; i < kCL; ++i) x[i] = ip[(size_t)i * kQPB];

  float4 cs = make_float4(0.f, 0.f, 0.f, 0.f);
#pragma unroll
  for (int i = 0; i < kCL; ++i) {
    cs.x += x[i].x; cs.y += x[i].y; cs.z += x[i].z; cs.w += x[i].w;
  }

  // Phase 2: exclusive prefix of chunk sums for this quad.
  csums[c][ql] = cs;
  __syncthreads();

  float4 cum = make_float4(0.f, 0.f, 0.f, 0.f);
  for (int cc = 0; cc < c; ++cc) {
    const float4 p = csums[cc][ql];
    cum.x += p.x; cum.y += p.y; cum.z += p.z; cum.w += p.w;
  }

  // Phase 3: emit floor-diffs.
  float4 pf;
  pf.x = floorf(cum.x); pf.y = floorf(cum.y);
  pf.z = floorf(cum.z); pf.w = floorf(cum.w);

#pragma unroll
  for (int i = 0; i < kCL; ++i) {
    float4 s;
    cum.x += x[i].x; { float nf = floorf(cum.x); s.x = nf - pf.x; pf.x = nf; }
    cum.y += x[i].y; { float nf = floorf(cum.y); s.y = nf - pf.y; pf.y = nf; }
    cum.z += x[i].z; { float nf = floorf(cum.z); s.z = nf - pf.z; pf.z = nf; }
    cum.w += x[i].w; { float nf = floorf(cum.w); s.w = nf - pf.w; pf.w = nf; }
    op[(size_t)i * kQPB] = s;
  }
}

extern "C" void kernel_launch(void* const* d_in, const int* in_sizes, int n_in,
                              void* d_out, int out_size, void* d_ws, size_t ws_size,
                              hipStream_t stream) {
  (void)in_sizes; (void)n_in; (void)d_ws; (void)ws_size; (void)out_size;
  const float4* in = (const float4*)d_in[0];
  float4* out = (float4*)d_out;

  const int total_quads = 8 * kQPB;                  // 65536
  const int grid = total_quads / kQPBlk;             // 2048 blocks
  iaf_scan_kernel<<<grid, 256, 0, stream>>>(in, out);
}